// Round 1
// baseline (353.972 us; speedup 1.0000x reference)
//
#include <hip/hip_runtime.h>

#define GLOBAL_AS __attribute__((address_space(1)))
#define LDS_AS __attribute__((address_space(3)))

typedef unsigned short u16;
typedef unsigned int u32;
typedef __bf16 bf16x8 __attribute__((ext_vector_type(8)));
typedef float f32x4 __attribute__((ext_vector_type(4)));

static constexpr int BB = 8;        // batch
static constexpr int TT = 2048;     // time
static constexpr int DD = 1024;     // feature dim
static constexpr int MM = BB * TT;  // 16384 rows
static constexpr int KK = DD;       // 1024
static constexpr int NC = 32;       // scan chunks per sequence
static constexpr int CL = TT / NC;  // 64 timesteps per chunk

__device__ __forceinline__ u16 f2bf(float f) {
  union { float f; u32 u; } c; c.f = f;
  u32 u = c.u;
  u32 r = (u + 0x7fffu + ((u >> 16) & 1u)) >> 16;  // RNE
  return (u16)r;
}

// ---------------- pass 0a: x fp32 -> bf16 ----------------
__global__ void cvt_x_kernel(const float* __restrict__ x, u16* __restrict__ xb) {
  int i = (blockIdx.x * blockDim.x + threadIdx.x) * 8;
  const float4* p = reinterpret_cast<const float4*>(x + i);
  float4 v0 = p[0], v1 = p[1];
  u16 r0 = f2bf(v0.x), r1 = f2bf(v0.y), r2 = f2bf(v0.z), r3 = f2bf(v0.w);
  u16 r4 = f2bf(v1.x), r5 = f2bf(v1.y), r6 = f2bf(v1.z), r7 = f2bf(v1.w);
  uint4 o;
  o.x = (u32)r0 | ((u32)r1 << 16);
  o.y = (u32)r2 | ((u32)r3 << 16);
  o.z = (u32)r4 | ((u32)r5 << 16);
  o.w = (u32)r6 | ((u32)r7 << 16);
  *reinterpret_cast<uint4*>(xb + i) = o;
}

// ---------------- pass 0b: W fp32 [k][n] -> bf16 W^T [n][k] ----------------
__global__ void cvt_w_kernel(const float* __restrict__ Wz, const float* __restrict__ Wh,
                             u16* __restrict__ WT) {
  __shared__ float tile[32][33];
  int w = blockIdx.z;
  const float* W = w ? Wh : Wz;
  u16* O = WT + (size_t)w * DD * KK;
  int k0 = blockIdx.y * 32;
  int n0 = blockIdx.x * 32;
  int tx = threadIdx.x, ty = threadIdx.y;
  for (int i = 0; i < 32; i += 8)
    tile[ty + i][tx] = W[(size_t)(k0 + ty + i) * DD + n0 + tx];
  __syncthreads();
  for (int i = 0; i < 32; i += 8)
    O[(size_t)(n0 + ty + i) * KK + k0 + tx] = f2bf(tile[tx][ty + i]);
}

// ---------------- pass 1: dual GEMM + gate epilogue ----------------
// zpre = x*Wz + bz ; hpre = x*Wh + bh ; a = 1-sigmoid(zpre) ; b = sigmoid(zpre)*hpre
__global__ __launch_bounds__(256) void gemm_dual_kernel(
    const u16* __restrict__ xb,   // [MM][KK] bf16
    const u16* __restrict__ WT,   // [2][DD][KK] bf16 (n-major)
    const float* __restrict__ bz, const float* __restrict__ bh,
    float* __restrict__ a_out, float* __restrict__ bb_out) {
  __shared__ __align__(16) u16 As[64 * 32];
  __shared__ __align__(16) u16 Bzs[64 * 32];
  __shared__ __align__(16) u16 Bhs[64 * 32];

  int bid = blockIdx.x;
  int nt = bid & 15;    // 16 n-tiles  (same-m blocks adjacent -> share W tiles in L2)
  int mt = bid >> 4;    // 256 m-tiles
  int m0 = mt * 64, n0 = nt * 64;

  int tid = threadIdx.x;
  int lane = tid & 63;
  int wave = tid >> 6;

  // staging: dest flat bf16 elem = tid*8 ; row = tid>>2 ; k-seg = (tid&3)*8
  int drow = tid >> 2;
  int dk = (tid & 3) * 8;
  const u16* Ag  = xb + (size_t)(m0 + drow) * KK + dk;
  const u16* Bzg = WT + (size_t)(n0 + drow) * KK + dk;
  const u16* Bhg = WT + (size_t)DD * KK + (size_t)(n0 + drow) * KK + dk;

  u16* AsW  = As  + wave * 512;   // wave-uniform LDS base, lane i lands at +i*16B
  u16* BzsW = Bzs + wave * 512;
  u16* BhsW = Bhs + wave * 512;

  f32x4 accz[2][2];
  f32x4 acch[2][2];
  for (int i = 0; i < 2; i++)
    for (int j = 0; j < 2; j++) {
      accz[i][j] = (f32x4){0.f, 0.f, 0.f, 0.f};
      acch[i][j] = (f32x4){0.f, 0.f, 0.f, 0.f};
    }

  int RM = (wave >> 1) * 32;   // wave quadrant rows
  int RN = (wave & 1) * 32;    // wave quadrant cols
  int fr = lane & 15;
  int fk = (lane >> 4) * 8;

  for (int k0i = 0; k0i < KK; k0i += 32) {
    __builtin_amdgcn_global_load_lds((const GLOBAL_AS void*)(Ag + k0i),  (LDS_AS void*)AsW,  16, 0, 0);
    __builtin_amdgcn_global_load_lds((const GLOBAL_AS void*)(Bzg + k0i), (LDS_AS void*)BzsW, 16, 0, 0);
    __builtin_amdgcn_global_load_lds((const GLOBAL_AS void*)(Bhg + k0i), (LDS_AS void*)BhsW, 16, 0, 0);
    __syncthreads();  // drains vmcnt -> staging visible

    bf16x8 af[2], bzf[2], bhf[2];
    for (int i = 0; i < 2; i++)
      af[i] = *reinterpret_cast<const bf16x8*>(As + (RM + i * 16 + fr) * 32 + fk);
    for (int j = 0; j < 2; j++) {
      bzf[j] = *reinterpret_cast<const bf16x8*>(Bzs + (RN + j * 16 + fr) * 32 + fk);
      bhf[j] = *reinterpret_cast<const bf16x8*>(Bhs + (RN + j * 16 + fr) * 32 + fk);
    }
    for (int i = 0; i < 2; i++)
      for (int j = 0; j < 2; j++) {
        accz[i][j] = __builtin_amdgcn_mfma_f32_16x16x32_bf16(af[i], bzf[j], accz[i][j], 0, 0, 0);
        acch[i][j] = __builtin_amdgcn_mfma_f32_16x16x32_bf16(af[i], bhf[j], acch[i][j], 0, 0, 0);
      }
    __syncthreads();  // tiles consumed before restage
  }

  // epilogue: D[row = RM+i*16+(lane>>4)*4+r][col = RN+j*16+(lane&15)]
  for (int j = 0; j < 2; j++) {
    int n = n0 + RN + j * 16 + fr;
    float bzv = bz[n], bhv = bh[n];
    for (int i = 0; i < 2; i++) {
      int mbase = m0 + RM + i * 16 + (lane >> 4) * 4;
      for (int r = 0; r < 4; r++) {
        int m = mbase + r;
        float zp = accz[i][j][r] + bzv;
        float hp = acch[i][j][r] + bhv;
        float zs = 1.0f / (1.0f + __expf(-zp));
        size_t idx = (size_t)m * DD + n;
        a_out[idx] = 1.0f - zs;
        bb_out[idx] = zs * hp;
      }
    }
  }
}

// ---------------- pass 2: per-chunk composition (A,B) ----------------
__global__ void chunk_reduce_kernel(const float* __restrict__ a, const float* __restrict__ bb,
                                    float* __restrict__ Asum, float* __restrict__ Bsum) {
  int tid = blockIdx.x * blockDim.x + threadIdx.x;  // [b][c][d] = 8*32*1024
  int d = tid & (DD - 1);
  int c = (tid >> 10) & (NC - 1);
  int b = tid >> 15;
  size_t base = ((size_t)b * TT + (size_t)c * CL) * DD + d;
  float A = 1.f, Bv = 0.f;
  for (int t = 0; t < CL; t++) {
    float av = a[base + (size_t)t * DD];
    float bv = bb[base + (size_t)t * DD];
    A *= av;
    Bv = av * Bv + bv;
  }
  Asum[tid] = A;
  Bsum[tid] = Bv;
}

// ---------------- pass 3: scan over chunk summaries -> h_in per chunk ----------------
__global__ void chunk_scan_kernel(const float* __restrict__ Asum, const float* __restrict__ Bsum,
                                  float* __restrict__ hin) {
  int tid = blockIdx.x * blockDim.x + threadIdx.x;  // 8192 = [b][d]
  int d = tid & (DD - 1);
  int b = tid >> 10;
  float h = 0.f;
  for (int c = 0; c < NC; c++) {
    int i = (b * NC + c) * DD + d;
    hin[i] = h;
    h = Asum[i] * h + Bsum[i];
  }
}

// ---------------- pass 4: apply recurrence + swish + fused LayerNorm ----------------
__global__ __launch_bounds__(1024) void apply_ln_kernel(
    const float* __restrict__ a, const float* __restrict__ bb, const float* __restrict__ hin,
    const float* __restrict__ sbeta, const float* __restrict__ gamma,
    const float* __restrict__ lbeta, float* __restrict__ out) {
  __shared__ float ps[2][16];
  __shared__ float pq[2][16];
  int d = threadIdx.x;
  int c = blockIdx.x & (NC - 1);
  int b = blockIdx.x >> 5;
  int lane = d & 63, wv = d >> 6;
  float sb = sbeta[0];
  float g = gamma[d], be = lbeta[d];
  float h = hin[(b * NC + c) * DD + d];
  size_t base = ((size_t)b * TT + (size_t)c * CL) * DD + d;

  // depth-2 prefetch ring to hide HBM latency behind the per-t reduction
  float aR[2], bR[2];
  aR[0] = a[base];               bR[0] = bb[base];
  aR[1] = a[base + DD];          bR[1] = bb[base + DD];

  for (int t = 0; t < CL; t++) {
    float av = aR[t & 1], bv = bR[t & 1];
    if (t + 2 < CL) {
      aR[t & 1] = a[base + (size_t)(t + 2) * DD];
      bR[t & 1] = bb[base + (size_t)(t + 2) * DD];
    }
    h = av * h + bv;
    float s = sb * h;
    float y = s / (1.0f + __expf(-s));

    float sum = y, sq = y * y;
    for (int o = 32; o > 0; o >>= 1) {
      sum += __shfl_xor(sum, o, 64);
      sq += __shfl_xor(sq, o, 64);
    }
    int slot = t & 1;
    if (lane == 0) { ps[slot][wv] = sum; pq[slot][wv] = sq; }
    __syncthreads();
    float tot = 0.f, totq = 0.f;
    for (int w2 = 0; w2 < 16; w2++) { tot += ps[slot][w2]; totq += pq[slot][w2]; }
    float mu = tot * (1.0f / DD);
    float var = totq * (1.0f / DD) - mu * mu;
    float inv = rsqrtf(fmaxf(var, 0.f) + 1e-5f);
    out[base + (size_t)t * DD] = (y - mu) * inv * g + be;
  }
}

extern "C" void kernel_launch(void* const* d_in, const int* in_sizes, int n_in,
                              void* d_out, int out_size, void* d_ws, size_t ws_size,
                              hipStream_t stream) {
  const float* x     = (const float*)d_in[0];
  const float* Wz    = (const float*)d_in[1];
  const float* bz    = (const float*)d_in[2];
  const float* Wh    = (const float*)d_in[3];
  const float* bh    = (const float*)d_in[4];
  const float* sbeta = (const float*)d_in[5];
  const float* gamma = (const float*)d_in[6];
  const float* lbeta = (const float*)d_in[7];
  float* out = (float*)d_out;

  char* ws = (char*)d_ws;
  u16* xb    = (u16*)ws;                         // 33,554,432 B
  u16* WT    = (u16*)(ws + 33554432);            //  4,194,304 B
  float* bb  = (float*)(ws + 37748736);          // 67,108,864 B
  float* Asum = (float*)(ws + 104857600);        //  1,048,576 B
  float* Bsum = (float*)(ws + 105906176);        //  1,048,576 B
  float* hin  = (float*)(ws + 106954752);        //  1,048,576 B
  const size_t NEED_BASE = 108003328ull;
  const size_t NEED_FULL = NEED_BASE + 67108864ull;
  float* a_ptr = (ws_size >= NEED_FULL) ? (float*)(ws + NEED_BASE) : out;

  cvt_x_kernel<<<8192, 256, 0, stream>>>(x, xb);
  dim3 tw(32, 8), gw(32, 32, 2);
  cvt_w_kernel<<<gw, tw, 0, stream>>>(Wz, Wh, WT);
  gemm_dual_kernel<<<4096, 256, 0, stream>>>(xb, WT, bz, bh, a_ptr, bb);
  chunk_reduce_kernel<<<1024, 256, 0, stream>>>(a_ptr, bb, Asum, Bsum);
  chunk_scan_kernel<<<32, 256, 0, stream>>>(Asum, Bsum, hin);
  apply_ln_kernel<<<256, 1024, 0, stream>>>(a_ptr, bb, hin, sbeta, gamma, lbeta, out);
}